// Round 12
// baseline (274.149 us; speedup 1.0000x reference)
//
#include <hip/hip_runtime.h>

// ---------------------------------------------------------------------------
// R12: numerics frozen from R6 (PASS, absmax 1.95e-3). Perf target: fc1_panel
// (83 us). Diagnosis: ds_read_b128-pipe-bound (3 b128 per thread-k at ~12cyc
// on the CU-shared LDS pipe = 144k cyc/CU vs 64k VALU) + 4-way As bank
// conflicts (9.96e6 cyc). Fix (tiling only — per-element k-chain unchanged):
//  - 8x8 microtile / 128x128 tile (grid 4x8x15): LDS instrs per MAC 1.5x down.
//  - group-packed LDS rows (pad 4 per 8 floats): compute reads 2-way max=free.
// conv1 / conv2(+wt) / snn_loop unchanged from R11.
// ---------------------------------------------------------------------------

// ---------------------------------------------------------------------------
// Kernel 0: conv2 weight transpose -> per-wave K-major. UNCHANGED.
// ---------------------------------------------------------------------------
__global__ void __launch_bounds__(256) conv2_wt(
    const float* __restrict__ w, float* __restrict__ wt) {
  int tid = blockIdx.x * 256 + threadIdx.x;
  if (tid >= 64 * 288) return;
  int i = tid & 15;
  int node = tid >> 4;
  int kk = node % 9;
  int gic = node / 9;
  int ic = gic & 31, g = gic >> 5;
  wt[tid] = w[(size_t)(g * 16 + i) * 288 + ic * 9 + kk];
}

// ---------------------------------------------------------------------------
// Kernel 1: conv1 (3->32) + bias + ReLU + 2x2 maxpool. UNCHANGED.
// ---------------------------------------------------------------------------
__global__ void __launch_bounds__(256) conv1_pool(
    const float* __restrict__ x, const float* __restrict__ w,
    const float* __restrict__ bias, float* __restrict__ p1) {
  const int b = blockIdx.x;
  __shared__ float sx[3 * 34 * 34];
  const float* xb = x + (size_t)b * 3072;
  for (int i = threadIdx.x; i < 3 * 34 * 34; i += 256) sx[i] = 0.0f;
  __syncthreads();
  for (int i = threadIdx.x; i < 3072; i += 256) {
    int ic = i >> 10, y = (i >> 5) & 31, xx = i & 31;
    sx[ic * 1156 + (y + 1) * 34 + (xx + 1)] = xb[i];
  }
  __syncthreads();

  const int px = threadIdx.x & 15, py = threadIdx.x >> 4;
  float xr[3][4][4];
#pragma unroll
  for (int ic = 0; ic < 3; ic++)
#pragma unroll
    for (int r = 0; r < 4; r++)
#pragma unroll
      for (int c = 0; c < 4; c++)
        xr[ic][r][c] = sx[ic * 1156 + (2 * py + r) * 34 + (2 * px + c)];

  float* outp = p1 + (size_t)b * 8192 + py * 16 + px;
  for (int oc = 0; oc < 32; oc++) {
    const float* wo = w + oc * 27;
    float a0 = 0.0f, a1 = 0.0f, a2 = 0.0f, a3 = 0.0f;
#pragma unroll
    for (int ky = 0; ky < 3; ky++)
#pragma unroll
      for (int kx = 0; kx < 3; kx++)
#pragma unroll
        for (int ic = 0; ic < 3; ic++) {  // ic innermost (HWIO im2col order)
          float wv = wo[ic * 9 + ky * 3 + kx];
          a0 = fmaf(wv, xr[ic][ky][kx], a0);
          a1 = fmaf(wv, xr[ic][ky][kx + 1], a1);
          a2 = fmaf(wv, xr[ic][ky + 1][kx], a2);
          a3 = fmaf(wv, xr[ic][ky + 1][kx + 1], a3);
        }
    float bv = bias[oc];
    a0 = fmaxf(__fadd_rn(a0, bv), 0.0f);
    a1 = fmaxf(__fadd_rn(a1, bv), 0.0f);
    a2 = fmaxf(__fadd_rn(a2, bv), 0.0f);
    a3 = fmaxf(__fadd_rn(a3, bv), 0.0f);
    outp[oc * 256] = fmaxf(fmaxf(a0, a1), fmaxf(a2, a3));
  }
}

// ---------------------------------------------------------------------------
// Kernel 2: conv2 (32->64) + bias + ReLU + pool, K-major weights. UNCHANGED.
// ---------------------------------------------------------------------------
__global__ void __launch_bounds__(256) conv2_pool(
    const float* __restrict__ p1, const float* __restrict__ wt,
    const float* __restrict__ bias, float* __restrict__ p2) {
  const int b = blockIdx.x;
  __shared__ float sx[32 * 18 * 18];  // 41472 B
  const float* xb = p1 + (size_t)b * 8192;
  for (int i = threadIdx.x; i < 32 * 18 * 18; i += 256) sx[i] = 0.0f;
  __syncthreads();
  for (int i = threadIdx.x; i < 8192; i += 256) {
    int ic = i >> 8, y = (i >> 4) & 15, xx = i & 15;
    sx[ic * 324 + (y + 1) * 18 + (xx + 1)] = xb[i];
  }
  __syncthreads();

  const int t = threadIdx.x;
  const int px = t & 7, py = (t >> 3) & 7;
  const int g = __builtin_amdgcn_readfirstlane(t >> 6);  // wave 0..3
  const float* wg = wt + (size_t)g * 32 * 9 * 16;        // wave's K-stream

  float acc[16][4];
#pragma unroll
  for (int i = 0; i < 16; i++)
    acc[i][0] = acc[i][1] = acc[i][2] = acc[i][3] = 0.0f;

#pragma unroll
  for (int ky = 0; ky < 3; ky++) {
#pragma unroll
    for (int kx = 0; kx < 3; kx++) {
      const int r0 = (2 * py + ky) * 18 + 2 * px + kx;
      const int r1 = r0 + 18;
#pragma unroll 4
      for (int ic = 0; ic < 32; ic++) {  // ic innermost (chain order)
        float x00 = sx[ic * 324 + r0];
        float x01 = sx[ic * 324 + r0 + 1];
        float x10 = sx[ic * 324 + r1];
        float x11 = sx[ic * 324 + r1 + 1];
        const float* wp = wg + (size_t)(ic * 9 + ky * 3 + kx) * 16;
#pragma unroll
        for (int i = 0; i < 16; i++) {
          float wv = wp[i];  // wave-uniform contiguous -> s_load
          acc[i][0] = fmaf(wv, x00, acc[i][0]);
          acc[i][1] = fmaf(wv, x01, acc[i][1]);
          acc[i][2] = fmaf(wv, x10, acc[i][2]);
          acc[i][3] = fmaf(wv, x11, acc[i][3]);
        }
      }
    }
  }

  float* outb = p2 + (size_t)b * 4096;
#pragma unroll
  for (int i = 0; i < 16; i++) {
    float bv = bias[g * 16 + i];
    float a0 = fmaxf(__fadd_rn(acc[i][0], bv), 0.0f);
    float a1 = fmaxf(__fadd_rn(acc[i][1], bv), 0.0f);
    float a2 = fmaxf(__fadd_rn(acc[i][2], bv), 0.0f);
    float a3 = fmaxf(__fadd_rn(acc[i][3], bv), 0.0f);
    outb[(g * 16 + i) * 64 + py * 8 + px] = fmaxf(fmaxf(a0, a1), fmaxf(a2, a3));
  }
}

// ---------------------------------------------------------------------------
// Kernel 3: fc1 panel GEMM, split-K over Eigen kc=288 panels.
// R12: 128x128 tile, 8x8 microtile, grid (4,8,15). LDS rows group-packed:
// pack(m) = (m>>3)*12 + (m&7) (4-float pad per 8) -> compute-read banks
// 12*tx%32, 2-way max (free). Per-element k-chain identical to R6/R8.
// ---------------------------------------------------------------------------
__global__ void __launch_bounds__(256) fc1_panel(
    const float* __restrict__ A,   // h [512,4096]
    const float* __restrict__ W,   // [1000,4096]
    float* __restrict__ part) {    // [15,512,1000]
  __shared__ __align__(16) float As[16][192];  // 12288 B (packed 128)
  __shared__ __align__(16) float Bs[16][192];  // 12288 B (packed 128)
  const int t = threadIdx.x;
  const int m0 = blockIdx.x * 128, n0 = blockIdx.y * 128;
  const int z = blockIdx.z;
  const int k0 = z * 288;
  const int L = (z == 14) ? 64 : 288;

  // staging: thread -> (row lm = t>>1 of 128, k-offset lk = (t&1)*8)
  const int lm = t >> 1, lk = (t & 1) * 8;
  const int packlm = ((lm >> 3) * 12) + (lm & 7);
  const int nr = n0 + lm;
  const float* Ap = A + (size_t)(m0 + lm) * 4096 + k0 + lk;
  const float* Bp = W + (size_t)(nr < 1000 ? nr : 0) * 4096 + k0 + lk;
  const int tx = t & 15, ty = t >> 4;  // tx: m-group of 8, ty: n-group of 8

  float acc[8][8];
#pragma unroll
  for (int i = 0; i < 8; i++)
#pragma unroll
    for (int j = 0; j < 8; j++) acc[i][j] = 0.0f;

  for (int kk = 0; kk < L; kk += 16) {
    float4 a0 = *(const float4*)Ap;
    float4 a1 = *(const float4*)(Ap + 4);
    float4 b0 = *(const float4*)Bp;
    float4 b1 = *(const float4*)(Bp + 4);
    As[lk + 0][packlm] = a0.x; As[lk + 1][packlm] = a0.y;
    As[lk + 2][packlm] = a0.z; As[lk + 3][packlm] = a0.w;
    As[lk + 4][packlm] = a1.x; As[lk + 5][packlm] = a1.y;
    As[lk + 6][packlm] = a1.z; As[lk + 7][packlm] = a1.w;
    Bs[lk + 0][packlm] = b0.x; Bs[lk + 1][packlm] = b0.y;
    Bs[lk + 2][packlm] = b0.z; Bs[lk + 3][packlm] = b0.w;
    Bs[lk + 4][packlm] = b1.x; Bs[lk + 5][packlm] = b1.y;
    Bs[lk + 6][packlm] = b1.z; Bs[lk + 7][packlm] = b1.w;
    __syncthreads();
#pragma unroll 4
    for (int k = 0; k < 16; k++) {
      float4 av0 = *(const float4*)&As[k][tx * 12];
      float4 av1 = *(const float4*)&As[k][tx * 12 + 4];
      float4 bv0 = *(const float4*)&Bs[k][ty * 12];
      float4 bv1 = *(const float4*)&Bs[k][ty * 12 + 4];
      float am[8] = {av0.x, av0.y, av0.z, av0.w, av1.x, av1.y, av1.z, av1.w};
      float bn[8] = {bv0.x, bv0.y, bv0.z, bv0.w, bv1.x, bv1.y, bv1.z, bv1.w};
#pragma unroll
      for (int i = 0; i < 8; i++)
#pragma unroll
        for (int j = 0; j < 8; j++)
          acc[i][j] = fmaf(am[i], bn[j], acc[i][j]);
    }
    __syncthreads();
    Ap += 16; Bp += 16;
  }

  float* pp = part + (size_t)z * 512000;
#pragma unroll
  for (int i = 0; i < 8; i++) {
    const int m = m0 + tx * 8 + i;
#pragma unroll
    for (int j = 0; j < 8; j++) {
      const int n = n0 + ty * 8 + j;
      if (n < 1000) pp[(size_t)m * 1000 + n] = acc[i][j];
    }
  }
}

// ---------------------------------------------------------------------------
// Kernel 4: fused 10-step SNN. UNCHANGED from R10.
// ---------------------------------------------------------------------------
__global__ void __launch_bounds__(256) snn_loop(
    const float* __restrict__ part,   // [15,512,1000]
    const float* __restrict__ fc1_b,  // [1000]
    const float* __restrict__ fc2_w,  // [10,1000]
    const float* __restrict__ fc2_b,  // [10]
    float* __restrict__ out) {        // [102400]
  const int b = blockIdx.x;
  const int t = threadIdx.x;
  __shared__ float pw[40 * 289];   // 46240 B
  __shared__ float spkp[4 * 289];  //  4624 B

  for (int i = t; i < 40 * 289; i += 256) {
    int chain = i / 289, ii = i - chain * 289;
    int o = chain % 10, c = chain / 10;
    int len = (c == 3) ? 136 : 288;
    pw[i] = (ii < len) ? fc2_w[o * 1000 + c * 288 + ii] : 0.0f;
  }

  float cur1[4], mem1[4];
#pragma unroll
  for (int q = 0; q < 4; q++) {
    int j = t + q * 256;
    float c = 0.0f;
    if (j < 1000) {
      const float* pb = part + (size_t)b * 1000 + j;
      float tot = pb[0];
#pragma unroll
      for (int p = 1; p < 15; p++)
        tot = __fadd_rn(tot, pb[(size_t)p * 512000]);
      c = __fadd_rn(tot, fc1_b[j]);
    }
    cur1[q] = c;
    mem1[q] = 0.0f;
  }
  float m2 = 0.0f;  // live only for t < 10
  __syncthreads();

  const int o4 = t % 10, c4 = t / 10;  // chain (o4, c4) for t < 40
  const float* wch = &pw[(c4 * 10 + o4) * 289];
  const float* sch = &spkp[c4 * 289];

  for (int s = 0; s < 10; s++) {
#pragma unroll
    for (int q = 0; q < 4; q++) {
      int j = t + q * 256;
      float m = mem1[q];
      float reset = (m > 1.0f) ? 1.0f : 0.0f;
      float t1 = __fmul_rn(0.95f, m);
      float t2 = __fadd_rn(t1, cur1[q]);
      m = __fsub_rn(t2, reset);
      mem1[q] = m;
      if (j < 1000) {
        int pc = (j >= 864) ? 3 : ((j >= 576) ? 2 : ((j >= 288) ? 1 : 0));
        spkp[pc * 289 + (j - pc * 288)] = (m > 1.0f) ? 1.0f : 0.0f;
      }
    }
    __syncthreads();

    float acc = 0.0f;
    if (t < 40) {
      if (c4 < 3) {
#pragma unroll 16
        for (int i = 0; i < 288; i++) acc = fmaf(sch[i], wch[i], acc);
      } else {
#pragma unroll 17
        for (int i = 0; i < 136; i++) acc = fmaf(sch[i], wch[i], acc);
      }
    }

    if (t < 64) {
      float p0 = __shfl(acc, o4, 64);
      float p1 = __shfl(acc, 10 + o4, 64);
      float p2 = __shfl(acc, 20 + o4, 64);
      float p3 = __shfl(acc, 30 + o4, 64);
      if (t < 10) {
        float tot = p0;
        tot = __fadd_rn(tot, p1);
        tot = __fadd_rn(tot, p2);
        tot = __fadd_rn(tot, p3);
        float c2 = __fadd_rn(tot, fc2_b[t]);
        float r2 = (m2 > 1.0f) ? 1.0f : 0.0f;
        float u1 = __fmul_rn(0.95f, m2);
        float u2 = __fadd_rn(u1, c2);
        m2 = __fsub_rn(u2, r2);
        out[s * 5120 + b * 10 + t] = (m2 > 1.0f) ? 1.0f : 0.0f;  // spk2
        out[51200 + s * 5120 + b * 10 + t] = m2;                  // mem2
      }
    }
    __syncthreads();
  }
}

// ---------------------------------------------------------------------------
// Launch. Workspace (39.2 MB peak, aliased):
//   part [0, 30.72M)       — fc1 panel partials [15,512,1000] fp32
//   p1   [0, 16M)          — conv1 out (dead before fc1 writes part)
//   h    [30.72M, 39.1M)   — conv2 out (live through fc1)
//   wt   [39.1M, 39.2M)    — transposed conv2 weights (18432 fp32)
// ---------------------------------------------------------------------------
extern "C" void kernel_launch(void* const* d_in, const int* in_sizes, int n_in,
                              void* d_out, int out_size, void* d_ws,
                              size_t ws_size, hipStream_t stream) {
  const float* x   = (const float*)d_in[0];
  const float* c1w = (const float*)d_in[1];
  const float* c1b = (const float*)d_in[2];
  const float* c2w = (const float*)d_in[3];
  const float* c2b = (const float*)d_in[4];
  const float* f1w = (const float*)d_in[5];
  const float* f1b = (const float*)d_in[6];
  const float* f2w = (const float*)d_in[7];
  const float* f2b = (const float*)d_in[8];
  float* out = (float*)d_out;

  char* ws = (char*)d_ws;
  float* part = (float*)(ws);                        // [15,512,1000] = 30.72 MB
  float* p1   = (float*)(ws);                        // alias (dead early)
  float* h    = (float*)(ws + (size_t)15 * 512 * 1000 * 4);       // [512,4096]
  float* wt   = (float*)(ws + (size_t)15 * 512 * 1000 * 4 + (size_t)512 * 4096 * 4);

  conv2_wt<<<72, 256, 0, stream>>>(c2w, wt);
  conv1_pool<<<512, 256, 0, stream>>>(x, c1w, c1b, p1);
  conv2_pool<<<512, 256, 0, stream>>>(p1, wt, c2b, h);
  fc1_panel<<<dim3(4, 8, 15), 256, 0, stream>>>(h, f1w, part);
  snn_loop<<<512, 256, 0, stream>>>(part, f1b, f2w, f2b, out);
}

// Round 13
// 270.271 us; speedup vs baseline: 1.0144x; 1.0144x over previous
//
#include <hip/hip_runtime.h>

// ---------------------------------------------------------------------------
// R13: numerics frozen from R6 (PASS, absmax 1.95e-3). Perf target: fc1_panel.
// R12 post-mortem: 128x128/8x8 tile has the right LDS budget (1.0 B/MAC ~= 
// VALU floor) but occupancy fell to 15.7% (480 blocks) and each k-step's
// staging exposed global-load latency at the barrier -> 87.8 us, VALUBusy 35%.
// Fix: REGISTER PREFETCH double-buffering — issue k-step n+1's global loads
// right after the first barrier, compute k-step n from LDS, then write the
// prefetched regs to LDS. vmcnt-wait lands after ~2048 VALU-cyc of compute.
// Load scheduling only — FMA chains bit-identical.
// conv1 / conv2(+wt) / snn_loop unchanged.
// ---------------------------------------------------------------------------

// ---------------------------------------------------------------------------
// Kernel 0: conv2 weight transpose -> per-wave K-major. UNCHANGED.
// ---------------------------------------------------------------------------
__global__ void __launch_bounds__(256) conv2_wt(
    const float* __restrict__ w, float* __restrict__ wt) {
  int tid = blockIdx.x * 256 + threadIdx.x;
  if (tid >= 64 * 288) return;
  int i = tid & 15;
  int node = tid >> 4;
  int kk = node % 9;
  int gic = node / 9;
  int ic = gic & 31, g = gic >> 5;
  wt[tid] = w[(size_t)(g * 16 + i) * 288 + ic * 9 + kk];
}

// ---------------------------------------------------------------------------
// Kernel 1: conv1 (3->32) + bias + ReLU + 2x2 maxpool. UNCHANGED.
// ---------------------------------------------------------------------------
__global__ void __launch_bounds__(256) conv1_pool(
    const float* __restrict__ x, const float* __restrict__ w,
    const float* __restrict__ bias, float* __restrict__ p1) {
  const int b = blockIdx.x;
  __shared__ float sx[3 * 34 * 34];
  const float* xb = x + (size_t)b * 3072;
  for (int i = threadIdx.x; i < 3 * 34 * 34; i += 256) sx[i] = 0.0f;
  __syncthreads();
  for (int i = threadIdx.x; i < 3072; i += 256) {
    int ic = i >> 10, y = (i >> 5) & 31, xx = i & 31;
    sx[ic * 1156 + (y + 1) * 34 + (xx + 1)] = xb[i];
  }
  __syncthreads();

  const int px = threadIdx.x & 15, py = threadIdx.x >> 4;
  float xr[3][4][4];
#pragma unroll
  for (int ic = 0; ic < 3; ic++)
#pragma unroll
    for (int r = 0; r < 4; r++)
#pragma unroll
      for (int c = 0; c < 4; c++)
        xr[ic][r][c] = sx[ic * 1156 + (2 * py + r) * 34 + (2 * px + c)];

  float* outp = p1 + (size_t)b * 8192 + py * 16 + px;
  for (int oc = 0; oc < 32; oc++) {
    const float* wo = w + oc * 27;
    float a0 = 0.0f, a1 = 0.0f, a2 = 0.0f, a3 = 0.0f;
#pragma unroll
    for (int ky = 0; ky < 3; ky++)
#pragma unroll
      for (int kx = 0; kx < 3; kx++)
#pragma unroll
        for (int ic = 0; ic < 3; ic++) {  // ic innermost (HWIO im2col order)
          float wv = wo[ic * 9 + ky * 3 + kx];
          a0 = fmaf(wv, xr[ic][ky][kx], a0);
          a1 = fmaf(wv, xr[ic][ky][kx + 1], a1);
          a2 = fmaf(wv, xr[ic][ky + 1][kx], a2);
          a3 = fmaf(wv, xr[ic][ky + 1][kx + 1], a3);
        }
    float bv = bias[oc];
    a0 = fmaxf(__fadd_rn(a0, bv), 0.0f);
    a1 = fmaxf(__fadd_rn(a1, bv), 0.0f);
    a2 = fmaxf(__fadd_rn(a2, bv), 0.0f);
    a3 = fmaxf(__fadd_rn(a3, bv), 0.0f);
    outp[oc * 256] = fmaxf(fmaxf(a0, a1), fmaxf(a2, a3));
  }
}

// ---------------------------------------------------------------------------
// Kernel 2: conv2 (32->64) + bias + ReLU + pool, K-major weights. UNCHANGED.
// ---------------------------------------------------------------------------
__global__ void __launch_bounds__(256) conv2_pool(
    const float* __restrict__ p1, const float* __restrict__ wt,
    const float* __restrict__ bias, float* __restrict__ p2) {
  const int b = blockIdx.x;
  __shared__ float sx[32 * 18 * 18];  // 41472 B
  const float* xb = p1 + (size_t)b * 8192;
  for (int i = threadIdx.x; i < 32 * 18 * 18; i += 256) sx[i] = 0.0f;
  __syncthreads();
  for (int i = threadIdx.x; i < 8192; i += 256) {
    int ic = i >> 8, y = (i >> 4) & 15, xx = i & 15;
    sx[ic * 324 + (y + 1) * 18 + (xx + 1)] = xb[i];
  }
  __syncthreads();

  const int t = threadIdx.x;
  const int px = t & 7, py = (t >> 3) & 7;
  const int g = __builtin_amdgcn_readfirstlane(t >> 6);  // wave 0..3
  const float* wg = wt + (size_t)g * 32 * 9 * 16;        // wave's K-stream

  float acc[16][4];
#pragma unroll
  for (int i = 0; i < 16; i++)
    acc[i][0] = acc[i][1] = acc[i][2] = acc[i][3] = 0.0f;

#pragma unroll
  for (int ky = 0; ky < 3; ky++) {
#pragma unroll
    for (int kx = 0; kx < 3; kx++) {
      const int r0 = (2 * py + ky) * 18 + 2 * px + kx;
      const int r1 = r0 + 18;
#pragma unroll 4
      for (int ic = 0; ic < 32; ic++) {  // ic innermost (chain order)
        float x00 = sx[ic * 324 + r0];
        float x01 = sx[ic * 324 + r0 + 1];
        float x10 = sx[ic * 324 + r1];
        float x11 = sx[ic * 324 + r1 + 1];
        const float* wp = wg + (size_t)(ic * 9 + ky * 3 + kx) * 16;
#pragma unroll
        for (int i = 0; i < 16; i++) {
          float wv = wp[i];  // wave-uniform contiguous -> s_load
          acc[i][0] = fmaf(wv, x00, acc[i][0]);
          acc[i][1] = fmaf(wv, x01, acc[i][1]);
          acc[i][2] = fmaf(wv, x10, acc[i][2]);
          acc[i][3] = fmaf(wv, x11, acc[i][3]);
        }
      }
    }
  }

  float* outb = p2 + (size_t)b * 4096;
#pragma unroll
  for (int i = 0; i < 16; i++) {
    float bv = bias[g * 16 + i];
    float a0 = fmaxf(__fadd_rn(acc[i][0], bv), 0.0f);
    float a1 = fmaxf(__fadd_rn(acc[i][1], bv), 0.0f);
    float a2 = fmaxf(__fadd_rn(acc[i][2], bv), 0.0f);
    float a3 = fmaxf(__fadd_rn(acc[i][3], bv), 0.0f);
    outb[(g * 16 + i) * 64 + py * 8 + px] = fmaxf(fmaxf(a0, a1), fmaxf(a2, a3));
  }
}

// ---------------------------------------------------------------------------
// Kernel 3: fc1 panel GEMM, split-K over Eigen kc=288 panels.
// 128x128 tile, 8x8 microtile, grid (4,8,15), group-packed LDS rows
// (pack(m)=(m>>3)*12+(m&7)), REGISTER-PREFETCH pipeline:
//   regs = load(k0); loop { LDS <- regs; barrier; regs = load(k+1);
//                           compute(LDS); barrier; }
// Per-element k-chain identical to R6/R8.
// ---------------------------------------------------------------------------
__global__ void __launch_bounds__(256) fc1_panel(
    const float* __restrict__ A,   // h [512,4096]
    const float* __restrict__ W,   // [1000,4096]
    float* __restrict__ part) {    // [15,512,1000]
  __shared__ __align__(16) float As[16][192];  // 12288 B (packed 128)
  __shared__ __align__(16) float Bs[16][192];  // 12288 B (packed 128)
  const int t = threadIdx.x;
  const int m0 = blockIdx.x * 128, n0 = blockIdx.y * 128;
  const int z = blockIdx.z;
  const int k0 = z * 288;
  const int L = (z == 14) ? 64 : 288;

  const int lm = t >> 1, lk = (t & 1) * 8;
  const int packlm = ((lm >> 3) * 12) + (lm & 7);
  const int nr = n0 + lm;
  const float* Ap = A + (size_t)(m0 + lm) * 4096 + k0 + lk;
  const float* Bp = W + (size_t)(nr < 1000 ? nr : 0) * 4096 + k0 + lk;
  const int tx = t & 15, ty = t >> 4;  // tx: m-group of 8, ty: n-group of 8

  float acc[8][8];
#pragma unroll
  for (int i = 0; i < 8; i++)
#pragma unroll
    for (int j = 0; j < 8; j++) acc[i][j] = 0.0f;

  // prefetch k-step 0
  float4 ra0 = *(const float4*)Ap;
  float4 ra1 = *(const float4*)(Ap + 4);
  float4 rb0 = *(const float4*)Bp;
  float4 rb1 = *(const float4*)(Bp + 4);
  Ap += 16; Bp += 16;

  for (int kk = 0; kk < L; kk += 16) {
    // stage prefetched regs -> LDS
    As[lk + 0][packlm] = ra0.x; As[lk + 1][packlm] = ra0.y;
    As[lk + 2][packlm] = ra0.z; As[lk + 3][packlm] = ra0.w;
    As[lk + 4][packlm] = ra1.x; As[lk + 5][packlm] = ra1.y;
    As[lk + 6][packlm] = ra1.z; As[lk + 7][packlm] = ra1.w;
    Bs[lk + 0][packlm] = rb0.x; Bs[lk + 1][packlm] = rb0.y;
    Bs[lk + 2][packlm] = rb0.z; Bs[lk + 3][packlm] = rb0.w;
    Bs[lk + 4][packlm] = rb1.x; Bs[lk + 5][packlm] = rb1.y;
    Bs[lk + 6][packlm] = rb1.z; Bs[lk + 7][packlm] = rb1.w;
    __syncthreads();

    // issue next k-step's global loads (latency hidden behind compute below)
    if (kk + 16 < L) {
      ra0 = *(const float4*)Ap;
      ra1 = *(const float4*)(Ap + 4);
      rb0 = *(const float4*)Bp;
      rb1 = *(const float4*)(Bp + 4);
      Ap += 16; Bp += 16;
    }

#pragma unroll 4
    for (int k = 0; k < 16; k++) {
      float4 av0 = *(const float4*)&As[k][tx * 12];
      float4 av1 = *(const float4*)&As[k][tx * 12 + 4];
      float4 bv0 = *(const float4*)&Bs[k][ty * 12];
      float4 bv1 = *(const float4*)&Bs[k][ty * 12 + 4];
      float am[8] = {av0.x, av0.y, av0.z, av0.w, av1.x, av1.y, av1.z, av1.w};
      float bn[8] = {bv0.x, bv0.y, bv0.z, bv0.w, bv1.x, bv1.y, bv1.z, bv1.w};
#pragma unroll
      for (int i = 0; i < 8; i++)
#pragma unroll
        for (int j = 0; j < 8; j++)
          acc[i][j] = fmaf(am[i], bn[j], acc[i][j]);
    }
    __syncthreads();
  }

  float* pp = part + (size_t)z * 512000;
#pragma unroll
  for (int i = 0; i < 8; i++) {
    const int m = m0 + tx * 8 + i;
#pragma unroll
    for (int j = 0; j < 8; j++) {
      const int n = n0 + ty * 8 + j;
      if (n < 1000) pp[(size_t)m * 1000 + n] = acc[i][j];
    }
  }
}

// ---------------------------------------------------------------------------
// Kernel 4: fused 10-step SNN. UNCHANGED from R10.
// ---------------------------------------------------------------------------
__global__ void __launch_bounds__(256) snn_loop(
    const float* __restrict__ part,   // [15,512,1000]
    const float* __restrict__ fc1_b,  // [1000]
    const float* __restrict__ fc2_w,  // [10,1000]
    const float* __restrict__ fc2_b,  // [10]
    float* __restrict__ out) {        // [102400]
  const int b = blockIdx.x;
  const int t = threadIdx.x;
  __shared__ float pw[40 * 289];   // 46240 B
  __shared__ float spkp[4 * 289];  //  4624 B

  for (int i = t; i < 40 * 289; i += 256) {
    int chain = i / 289, ii = i - chain * 289;
    int o = chain % 10, c = chain / 10;
    int len = (c == 3) ? 136 : 288;
    pw[i] = (ii < len) ? fc2_w[o * 1000 + c * 288 + ii] : 0.0f;
  }

  float cur1[4], mem1[4];
#pragma unroll
  for (int q = 0; q < 4; q++) {
    int j = t + q * 256;
    float c = 0.0f;
    if (j < 1000) {
      const float* pb = part + (size_t)b * 1000 + j;
      float tot = pb[0];
#pragma unroll
      for (int p = 1; p < 15; p++)
        tot = __fadd_rn(tot, pb[(size_t)p * 512000]);
      c = __fadd_rn(tot, fc1_b[j]);
    }
    cur1[q] = c;
    mem1[q] = 0.0f;
  }
  float m2 = 0.0f;  // live only for t < 10
  __syncthreads();

  const int o4 = t % 10, c4 = t / 10;  // chain (o4, c4) for t < 40
  const float* wch = &pw[(c4 * 10 + o4) * 289];
  const float* sch = &spkp[c4 * 289];

  for (int s = 0; s < 10; s++) {
#pragma unroll
    for (int q = 0; q < 4; q++) {
      int j = t + q * 256;
      float m = mem1[q];
      float reset = (m > 1.0f) ? 1.0f : 0.0f;
      float t1 = __fmul_rn(0.95f, m);
      float t2 = __fadd_rn(t1, cur1[q]);
      m = __fsub_rn(t2, reset);
      mem1[q] = m;
      if (j < 1000) {
        int pc = (j >= 864) ? 3 : ((j >= 576) ? 2 : ((j >= 288) ? 1 : 0));
        spkp[pc * 289 + (j - pc * 288)] = (m > 1.0f) ? 1.0f : 0.0f;
      }
    }
    __syncthreads();

    float acc = 0.0f;
    if (t < 40) {
      if (c4 < 3) {
#pragma unroll 16
        for (int i = 0; i < 288; i++) acc = fmaf(sch[i], wch[i], acc);
      } else {
#pragma unroll 17
        for (int i = 0; i < 136; i++) acc = fmaf(sch[i], wch[i], acc);
      }
    }

    if (t < 64) {
      float p0 = __shfl(acc, o4, 64);
      float p1 = __shfl(acc, 10 + o4, 64);
      float p2 = __shfl(acc, 20 + o4, 64);
      float p3 = __shfl(acc, 30 + o4, 64);
      if (t < 10) {
        float tot = p0;
        tot = __fadd_rn(tot, p1);
        tot = __fadd_rn(tot, p2);
        tot = __fadd_rn(tot, p3);
        float c2 = __fadd_rn(tot, fc2_b[t]);
        float r2 = (m2 > 1.0f) ? 1.0f : 0.0f;
        float u1 = __fmul_rn(0.95f, m2);
        float u2 = __fadd_rn(u1, c2);
        m2 = __fsub_rn(u2, r2);
        out[s * 5120 + b * 10 + t] = (m2 > 1.0f) ? 1.0f : 0.0f;  // spk2
        out[51200 + s * 5120 + b * 10 + t] = m2;                  // mem2
      }
    }
    __syncthreads();
  }
}

// ---------------------------------------------------------------------------
// Launch. Workspace (39.2 MB peak, aliased):
//   part [0, 30.72M)       — fc1 panel partials [15,512,1000] fp32
//   p1   [0, 16M)          — conv1 out (dead before fc1 writes part)
//   h    [30.72M, 39.1M)   — conv2 out (live through fc1)
//   wt   [39.1M, 39.2M)    — transposed conv2 weights (18432 fp32)
// ---------------------------------------------------------------------------
extern "C" void kernel_launch(void* const* d_in, const int* in_sizes, int n_in,
                              void* d_out, int out_size, void* d_ws,
                              size_t ws_size, hipStream_t stream) {
  const float* x   = (const float*)d_in[0];
  const float* c1w = (const float*)d_in[1];
  const float* c1b = (const float*)d_in[2];
  const float* c2w = (const float*)d_in[3];
  const float* c2b = (const float*)d_in[4];
  const float* f1w = (const float*)d_in[5];
  const float* f1b = (const float*)d_in[6];
  const float* f2w = (const float*)d_in[7];
  const float* f2b = (const float*)d_in[8];
  float* out = (float*)d_out;

  char* ws = (char*)d_ws;
  float* part = (float*)(ws);                        // [15,512,1000] = 30.72 MB
  float* p1   = (float*)(ws);                        // alias (dead early)
  float* h    = (float*)(ws + (size_t)15 * 512 * 1000 * 4);       // [512,4096]
  float* wt   = (float*)(ws + (size_t)15 * 512 * 1000 * 4 + (size_t)512 * 4096 * 4);

  conv2_wt<<<72, 256, 0, stream>>>(c2w, wt);
  conv1_pool<<<512, 256, 0, stream>>>(x, c1w, c1b, p1);
  conv2_pool<<<512, 256, 0, stream>>>(p1, wt, c2b, h);
  fc1_panel<<<dim3(4, 8, 15), 256, 0, stream>>>(h, f1w, part);
  snn_loop<<<512, 256, 0, stream>>>(part, f1b, f2w, f2b, out);
}